// Round 8
// baseline (999.495 us; speedup 1.0000x reference)
//
#include <hip/hip_runtime.h>
#include <math.h>

// ---------------------------------------------------------------------------
// Round 7->8: occupancy fixes for PV (64x128 tiles, 1296 blocks) and Gram
// (16-way split-K, 1296 blocks). Workspace re-laid out, peak 171.3 MB.
// ---------------------------------------------------------------------------

typedef unsigned short u16;
typedef short short4v __attribute__((ext_vector_type(4)));
typedef short short8v __attribute__((ext_vector_type(8)));
typedef float f32x4 __attribute__((ext_vector_type(4)));

__device__ __forceinline__ u16 f2bf(float f) {
    unsigned u = __float_as_uint(f);
    return (u16)((u + 0x7FFF + ((u >> 16) & 1)) >> 16);
}
__device__ __forceinline__ float bf2f(u16 h) {
    return __uint_as_float(((unsigned)h) << 16);
}

#define GLOAD16(g, l) __builtin_amdgcn_global_load_lds(                      \
    (const __attribute__((address_space(1))) void*)(g),                      \
    (__attribute__((address_space(3))) void*)(l), 16, 0, 0)

// ---------------- x -> channels-last bf16 ic4 (for conv1 MFMA) --------------
__global__ void x4cl_kernel(const float* __restrict__ x, u16* __restrict__ out)
{
    int i = blockIdx.x * 256 + threadIdx.x;   // 589824 pixels
    if (i >= 589824) return;
    u16 v[4];
    v[0] = f2bf(x[i]);
    v[1] = f2bf(x[589824 + i]);
    v[2] = f2bf(x[1179648 + i]);
    v[3] = 0;
    *(short4v*)(out + (size_t)i * 4) = *(short4v*)v;
}

// w1 [32][3][5][5] f32 -> wp1 [32][128] bf16, k = tap*4+ic (pad zeros)
__global__ void pack_w1_kernel(const float* __restrict__ w, u16* __restrict__ wp)
{
    int i = blockIdx.x * 256 + threadIdx.x;   // 4096
    if (i >= 4096) return;
    int oc = i >> 7, k = i & 127;
    int tap = k >> 2, ic = k & 3;
    u16 v = 0;
    if (tap < 25 && ic < 3) v = f2bf(w[oc * 75 + ic * 25 + tap]);
    wp[i] = v;
}

// ---------------- conv1 MFMA: 3->32, 5x5, s1, reflect pad2, ELU -------------
__global__ __launch_bounds__(256)
void conv1_mfma_kernel(const u16* __restrict__ x4, const u16* __restrict__ wp1,
                       const float* __restrict__ bias, u16* __restrict__ out)
{
    __shared__ __align__(16) u16 sIn[12 * 20 * 4];
    const int tid = threadIdx.x;
    const int lane = tid & 63;
    const int w = tid >> 6;
    const int lm = lane & 15;
    const int lk = lane >> 4;
    const int oy0 = blockIdx.y * 8, ox0 = blockIdx.x * 16;

    for (int u = tid; u < 240; u += 256) {
        int yt = u / 20, xt = u - yt * 20;
        int gy = oy0 - 2 + yt; gy = gy < 0 ? -gy : (gy >= 768 ? 1534 - gy : gy);
        int gx = ox0 - 2 + xt; gx = gx < 0 ? -gx : (gx >= 768 ? 1534 - gx : gx);
        *(short4v*)(sIn + u * 4) = *(const short4v*)(x4 + ((size_t)gy * 768 + gx) * 4);
    }
    int aoff[4][2];
#pragma unroll
    for (int ks = 0; ks < 4; ++ks) {
        int t0 = ks * 8 + lk * 2;
        int t1 = t0 + 1;
        if (t0 > 24) t0 = 24;
        if (t1 > 24) t1 = 24;
        int dy0 = t0 / 5, dx0 = t0 - 5 * dy0;
        int dy1 = t1 / 5, dx1 = t1 - 5 * dy1;
        aoff[ks][0] = (dy0 * 20 + dx0 + lm) * 4;
        aoff[ks][1] = (dy1 * 20 + dx1 + lm) * 4;
    }
    __syncthreads();

    f32x4 acc[2][2];
#pragma unroll
    for (int i = 0; i < 2; ++i)
#pragma unroll
        for (int j = 0; j < 2; ++j) acc[i][j] = (f32x4){0.f, 0.f, 0.f, 0.f};

#pragma unroll
    for (int ks = 0; ks < 4; ++ks) {
        short8v a[2], b[2];
#pragma unroll
        for (int fm = 0; fm < 2; ++fm) {
            int base = (w * 2 + fm) * 80;
            short4v lo = *(const short4v*)(sIn + base + aoff[ks][0]);
            short4v hi = *(const short4v*)(sIn + base + aoff[ks][1]);
            short8v av;
            av[0] = lo[0]; av[1] = lo[1]; av[2] = lo[2]; av[3] = lo[3];
            av[4] = hi[0]; av[5] = hi[1]; av[6] = hi[2]; av[7] = hi[3];
            a[fm] = av;
        }
#pragma unroll
        for (int fn = 0; fn < 2; ++fn)
            b[fn] = *(const short8v*)(wp1 + (size_t)(fn * 16 + lm) * 128 + ks * 32 + lk * 8);
#pragma unroll
        for (int fm = 0; fm < 2; ++fm)
#pragma unroll
            for (int fn = 0; fn < 2; ++fn)
                acc[fm][fn] = __builtin_amdgcn_mfma_f32_16x16x32_bf16(
                    a[fm], b[fn], acc[fm][fn], 0, 0, 0);
    }

#pragma unroll
    for (int fm = 0; fm < 2; ++fm) {
        int gy = oy0 + w * 2 + fm;
#pragma unroll
        for (int fn = 0; fn < 2; ++fn) {
            int oc = fn * 16 + lm;
            float bv = bias[oc];
#pragma unroll
            for (int i = 0; i < 4; ++i) {
                int xx = lk * 4 + i;
                float v = acc[fm][fn][i] + bv;
                v = v > 0.f ? v : expm1f(v);
                out[((size_t)gy * 768 + ox0 + xx) * 32 + oc] = f2bf(v);
            }
        }
    }
}

// ---------------- weight prepack: [oc][ic][3][3] f32 -> [oc][tap][ic] bf16 --
__global__ void pack_w_kernel(const float* __restrict__ w, u16* __restrict__ wp,
                              int OC, int IC)
{
    int idx = blockIdx.x * 256 + threadIdx.x;
    if (idx >= OC * 9 * IC) return;
    int oc = idx / (9 * IC);
    int r  = idx - oc * 9 * IC;
    int tap = r / IC;
    int ic  = r - tap * IC;
    wp[idx] = f2bf(w[((size_t)oc * IC + ic) * 9 + tap]);
}

// ---------------- MFMA implicit-GEMM conv (3x3, reflect pad 1) --------------
template<int FM, int FN, int NWM, int NWN, int S, int IC, int ICC, int ACT, int OUTF32>
__global__ __launch_bounds__(256)
void mfma_conv_kernel(const u16* __restrict__ in, const u16* __restrict__ wgtP,
                      const float* __restrict__ bias, void* __restrict__ out,
                      int H, int W, int Ho, int Wo, int OC)
{
    constexpr int TY = 7 * S + 3;
    constexpr int TX = 15 * S + 3;
    constexpr int NSLOT = ICC / 8;
    constexpr int SWMSK = NSLOT - 1;
    constexpr int KTOT = 9 * IC;
    __shared__ __align__(16) u16 sIn[TY * TX * ICC];

    const int tid  = threadIdx.x;
    const int lane = tid & 63;
    const int wid  = tid >> 6;
    const int wmi  = wid / NWN;
    const int wni  = wid % NWN;
    const int lm   = lane & 15;
    const int lk   = lane >> 4;
    const int noff = blockIdx.z * (NWN * FN * 16);

    f32x4 acc[FM][FN];
#pragma unroll
    for (int i = 0; i < FM; ++i)
#pragma unroll
        for (int j = 0; j < FN; ++j) acc[i][j] = (f32x4){0.f, 0.f, 0.f, 0.f};

    const int iy0 = blockIdx.y * 8 * S - 1;
    const int ix0 = blockIdx.x * 16 * S - 1;

    for (int c0 = 0; c0 < IC; c0 += ICC) {
        if (c0) __syncthreads();
        for (int u = tid; u < TY * TX * NSLOT; u += 256) {
            int yt = u / (TX * NSLOT);
            int r  = u - yt * (TX * NSLOT);
            int xt = r / NSLOT;
            int sl = r - xt * NSLOT;
            int gy = iy0 + yt; gy = gy < 0 ? -gy : (gy >= H ? 2 * H - 2 - gy : gy);
            int gx = ix0 + xt; gx = gx < 0 ? -gx : (gx >= W ? 2 * W - 2 - gx : gx);
            *(short8v*)((char*)sIn + (size_t)((yt * TX + xt) * NSLOT + (sl ^ (xt & SWMSK))) * 16) =
                *(const short8v*)(in + ((size_t)gy * W + gx) * IC + c0 + sl * 8);
        }
        __syncthreads();
#pragma unroll
        for (int tap = 0; tap < 9; ++tap) {
            const int dy = tap / 3, dx = tap % 3;
#pragma unroll
            for (int icw = 0; icw < ICC / 32; ++icw) {
                short8v a[FM], b[FN];
#pragma unroll
                for (int fm = 0; fm < FM; ++fm) {
                    int yt = (wmi * FM + fm) * S + dy;
                    int xt = lm * S + dx;
                    a[fm] = *(const short8v*)((const char*)sIn +
                        (size_t)((yt * TX + xt) * NSLOT + ((icw * 4 + lk) ^ (xt & SWMSK))) * 16);
                }
#pragma unroll
                for (int fn = 0; fn < FN; ++fn) {
                    int n = noff + wni * FN * 16 + fn * 16 + lm;
                    b[fn] = *(const short8v*)(wgtP + (size_t)n * KTOT + tap * IC + c0 + icw * 32 + lk * 8);
                }
#pragma unroll
                for (int fm = 0; fm < FM; ++fm)
#pragma unroll
                    for (int fn = 0; fn < FN; ++fn)
                        acc[fm][fn] = __builtin_amdgcn_mfma_f32_16x16x32_bf16(
                            a[fm], b[fn], acc[fm][fn], 0, 0, 0);
            }
        }
    }

#pragma unroll
    for (int fm = 0; fm < FM; ++fm) {
        int y = blockIdx.y * 8 + wmi * FM + fm;
#pragma unroll
        for (int fn = 0; fn < FN; ++fn) {
            int oc = noff + wni * FN * 16 + fn * 16 + lm;
            float bv = bias[oc];
#pragma unroll
            for (int i = 0; i < 4; ++i) {
                int x = blockIdx.x * 16 + lk * 4 + i;
                float v = acc[fm][fn][i] + bv;
                if (ACT == 0) v = v > 0.f ? v : 0.f;
                else          v = v > 0.f ? v : expm1f(v);
                size_t o = ((size_t)y * Wo + x) * OC + oc;
                if (OUTF32) ((float*)out)[o] = v;
                else        ((u16*)out)[o]   = f2bf(v);
            }
        }
    }
}

// channels-last f32 [36864][128] -> planar f32 [128][36864]
__global__ __launch_bounds__(256)
void cl2p_kernel(const float* __restrict__ in, float* __restrict__ out)
{
    __shared__ float t[32][130];
    const int tid = threadIdx.x;
    const int p0 = blockIdx.x * 32;
#pragma unroll
    for (int j = 0; j < 16; ++j) {
        int idx = j * 256 + tid;
        int px = idx >> 7, c = idx & 127;
        t[px][c] = in[(size_t)(p0 + px) * 128 + c];
    }
    __syncthreads();
#pragma unroll
    for (int j = 0; j < 16; ++j) {
        int c = j * 8 + (tid >> 5);
        int px = tid & 31;
        out[(size_t)c * 36864 + p0 + px] = t[px][c];
    }
}

// planar f32 [128][36864] -> channels-last bf16 [36864][128]
__global__ __launch_bounds__(256)
void p2cl_kernel(const float* __restrict__ in, u16* __restrict__ out)
{
    __shared__ float t[32][130];
    const int tid = threadIdx.x;
    const int p0 = blockIdx.x * 32;
#pragma unroll
    for (int j = 0; j < 16; ++j) {
        int c = j * 8 + (tid >> 5);
        int px = tid & 31;
        t[px][c] = in[(size_t)c * 36864 + p0 + px];
    }
    __syncthreads();
#pragma unroll
    for (int j = 0; j < 16; ++j) {
        int idx = j * 256 + tid;
        int px = idx >> 7, c = idx & 127;
        out[(size_t)(p0 + px) * 128 + c] = f2bf(t[px][c]);
    }
}

// ---------------- patch builders (h6 is channels-last bf16) -----------------
__global__ void build_patches_T(const u16* __restrict__ h6, const float* __restrict__ mask,
                                u16* __restrict__ fgpT, u16* __restrict__ bgpT)
{
    int idx = blockIdx.x * 256 + threadIdx.x;   // p*1152 + k
    if (idx >= 9216 * 1152) return;
    int p = idx / 1152, k = idx - p * 1152;
    int y = p / 96, x = p - y * 96;
    int c = k / 9, t = k - c * 9;
    int dy = t / 3, dx = t - dy * 3;
    int sy = y + dy - 1, sx = x + dx - 1;
    float v = 0.f, vm = 0.f;
    if (sy >= 0 && sy < 96 && sx >= 0 && sx < 96) {
        v  = bf2f(h6[((size_t)(2 * sy) * 192 + 2 * sx) * 128 + c]);
        vm = v * mask[(size_t)(2 * sy) * 192 + 2 * sx];
    }
    bgpT[idx] = f2bf(v);
    fgpT[idx] = f2bf(vm);
}

__global__ void build_patches_K(const u16* __restrict__ h6, const float* __restrict__ mask,
                                u16* __restrict__ fgpK, u16* __restrict__ bgpK)
{
    int idx = blockIdx.x * 256 + threadIdx.x;   // k*9216 + q
    if (idx >= 9216 * 1152) return;
    int k = idx / 9216, q = idx - k * 9216;
    int y = q / 96, x = q - y * 96;
    int c = k / 9, t = k - c * 9;
    int dy = t / 3, dx = t - dy * 3;
    int sy = y + dy - 1, sx = x + dx - 1;
    float v = 0.f, vm = 0.f;
    if (sy >= 0 && sy < 96 && sx >= 0 && sx < 96) {
        v  = bf2f(h6[((size_t)(2 * sy) * 192 + 2 * sx) * 128 + c]);
        vm = v * mask[(size_t)(2 * sy) * 192 + 2 * sx];
    }
    bgpK[idx] = f2bf(v);
    fgpK[idx] = f2bf(vm);
}

// ---------------- sexp: bf16 NT MFMA GEMM, 128x128, exp epilogue ------------
__global__ __launch_bounds__(256)
void mfma_nt_sexp_kernel(const u16* __restrict__ A, const u16* __restrict__ B,
                         int lda, int ldb, int K,
                         u16* __restrict__ outH, int ldo,
                         const float* __restrict__ scale_p,
                         float* __restrict__ rsP, int rcol0)
{
    __shared__ __align__(16) u16 As[128 * 64];
    __shared__ __align__(16) u16 Bs[128 * 64];
    const int tid  = threadIdx.x;
    const int wid  = tid >> 6;
    const int lane = tid & 63;
    const int wm = (wid >> 1) * 64;
    const int wn = (wid & 1) * 64;
    const size_t bm = (size_t)blockIdx.y * 128;
    const size_t bn = (size_t)blockIdx.x * 128;

    f32x4 acc[4][4];
#pragma unroll
    for (int i = 0; i < 4; ++i)
#pragma unroll
        for (int j = 0; j < 4; ++j)
            acc[i][j] = (f32x4){0.f, 0.f, 0.f, 0.f};

    const int lrow = lane >> 3;
    const int lcb  = ((lane & 7) << 4) ^ ((lrow & 7) << 4);
    const char* gA = (const char*)A + ((bm + wid * 32 + lrow) * (size_t)lda) * 2 + lcb;
    const char* gB = (const char*)B + ((bn + wid * 32 + lrow) * (size_t)ldb) * 2 + lcb;
    char* lA = (char*)As + (size_t)(wid * 32) * 128;
    char* lB = (char*)Bs + (size_t)(wid * 32) * 128;
    const size_t rsA = (size_t)lda * 16;
    const size_t rsB = (size_t)ldb * 16;

    for (int k0 = 0; k0 < K; k0 += 64) {
        __syncthreads();
#pragma unroll
        for (int j = 0; j < 4; ++j) {
            GLOAD16(gA + j * rsA + (size_t)k0 * 2, lA + j * 1024);
            GLOAD16(gB + j * rsB + (size_t)k0 * 2, lB + j * 1024);
        }
        __syncthreads();
#pragma unroll
        for (int ks = 0; ks < 2; ++ks) {
            short8v a[4], b[4];
#pragma unroll
            for (int f = 0; f < 4; ++f) {
                int ma = wm + f * 16 + (lane & 15);
                int kba = (ks * 64 + ((lane >> 4) * 16)) ^ ((ma & 7) << 4);
                a[f] = *(const short8v*)((const char*)As + ma * 128 + kba);
                int nb = wn + f * 16 + (lane & 15);
                int kbb = (ks * 64 + ((lane >> 4) * 16)) ^ ((nb & 7) << 4);
                b[f] = *(const short8v*)((const char*)Bs + nb * 128 + kbb);
            }
#pragma unroll
            for (int fm = 0; fm < 4; ++fm)
#pragma unroll
                for (int fn = 0; fn < 4; ++fn)
                    acc[fm][fn] = __builtin_amdgcn_mfma_f32_16x16x32_bf16(
                        a[fm], b[fn], acc[fm][fn], 0, 0, 0);
        }
    }

    const float scale = *scale_p;
    float rloc[4][4];
#pragma unroll
    for (int fm = 0; fm < 4; ++fm)
#pragma unroll
        for (int i = 0; i < 4; ++i) rloc[fm][i] = 0.f;
#pragma unroll
    for (int fm = 0; fm < 4; ++fm)
#pragma unroll
        for (int fn = 0; fn < 4; ++fn)
#pragma unroll
            for (int i = 0; i < 4; ++i) {
                int r = wm + fm * 16 + ((lane >> 4) * 4) + i;
                int c = wn + fn * 16 + (lane & 15);
                float e = __expf(scale * acc[fm][fn][i]);
                outH[(bm + r) * (size_t)ldo + bn + c] = f2bf(e);
                rloc[fm][i] += e;
            }
#pragma unroll
    for (int fm = 0; fm < 4; ++fm)
#pragma unroll
        for (int i = 0; i < 4; ++i) {
            float s = rloc[fm][i];
            s += __shfl_xor(s, 8, 64);
            s += __shfl_xor(s, 4, 64);
            s += __shfl_xor(s, 2, 64);
            s += __shfl_xor(s, 1, 64);
            if ((lane & 15) == 0)
                rsP[(bm + wm + fm * 16 + ((lane >> 4) * 4) + i) * 144 +
                    rcol0 + blockIdx.x * 2 + (wid & 1)] = s;
        }
}

// ---------------- PV: 64x128 tile, 4 waves (2x2, each 32x64) ----------------
// D[m][n] (+)= sum_k A[m][k]*B[n][k]; grid (N/128, M/64)
template<int ACCUM>
__global__ __launch_bounds__(256)
void pv64_kernel(const u16* __restrict__ A, const u16* __restrict__ B,
                 int lda, int ldb, int K, float* __restrict__ outF, int ldo)
{
    __shared__ __align__(16) u16 As[64 * 64];
    __shared__ __align__(16) u16 Bs[128 * 64];
    const int tid  = threadIdx.x;
    const int wid  = tid >> 6;
    const int lane = tid & 63;
    const int wm = (wid >> 1) * 32;
    const int wn = (wid & 1) * 64;
    const size_t bm = (size_t)blockIdx.y * 64;
    const size_t bn = (size_t)blockIdx.x * 128;

    f32x4 acc[2][4];
#pragma unroll
    for (int i = 0; i < 2; ++i)
#pragma unroll
        for (int j = 0; j < 4; ++j)
            acc[i][j] = (f32x4){0.f, 0.f, 0.f, 0.f};

    const int lrow = lane >> 3;
    const int lcb  = ((lane & 7) << 4) ^ ((lrow & 7) << 4);
    const char* gA = (const char*)A + ((bm + wid * 16 + lrow) * (size_t)lda) * 2 + lcb;
    const char* gB = (const char*)B + ((bn + wid * 32 + lrow) * (size_t)ldb) * 2 + lcb;
    char* lA = (char*)As + (size_t)(wid * 16) * 128;
    char* lB = (char*)Bs + (size_t)(wid * 32) * 128;
    const size_t rsA = (size_t)lda * 16;
    const size_t rsB = (size_t)ldb * 16;

    for (int k0 = 0; k0 < K; k0 += 64) {
        __syncthreads();
#pragma unroll
        for (int j = 0; j < 2; ++j)
            GLOAD16(gA + j * rsA + (size_t)k0 * 2, lA + j * 1024);
#pragma unroll
        for (int j = 0; j < 4; ++j)
            GLOAD16(gB + j * rsB + (size_t)k0 * 2, lB + j * 1024);
        __syncthreads();
#pragma unroll
        for (int ks = 0; ks < 2; ++ks) {
            short8v a[2], b[4];
#pragma unroll
            for (int f = 0; f < 2; ++f) {
                int ma = wm + f * 16 + (lane & 15);
                int kba = (ks * 64 + ((lane >> 4) * 16)) ^ ((ma & 7) << 4);
                a[f] = *(const short8v*)((const char*)As + ma * 128 + kba);
            }
#pragma unroll
            for (int f = 0; f < 4; ++f) {
                int nb = wn + f * 16 + (lane & 15);
                int kbb = (ks * 64 + ((lane >> 4) * 16)) ^ ((nb & 7) << 4);
                b[f] = *(const short8v*)((const char*)Bs + nb * 128 + kbb);
            }
#pragma unroll
            for (int fm = 0; fm < 2; ++fm)
#pragma unroll
                for (int fn = 0; fn < 4; ++fn)
                    acc[fm][fn] = __builtin_amdgcn_mfma_f32_16x16x32_bf16(
                        a[fm], b[fn], acc[fm][fn], 0, 0, 0);
        }
    }

#pragma unroll
    for (int fm = 0; fm < 2; ++fm)
#pragma unroll
        for (int fn = 0; fn < 4; ++fn)
#pragma unroll
            for (int i = 0; i < 4; ++i) {
                int r = wm + fm * 16 + ((lane >> 4) * 4) + i;
                int c = wn + fn * 16 + (lane & 15);
                float v = acc[fm][fn][i];
                if (ACCUM) outF[(bm + r) * (size_t)ldo + bn + c] += v;
                else       outF[(bm + r) * (size_t)ldo + bn + c]  = v;
            }
}

// ---------------- Gram kernel: grid (9,9,16); z = pair*8 + splitK -----------
__global__ __launch_bounds__(256)
void gram_kernel(const u16* __restrict__ F, const u16* __restrict__ Bg,
                 float* __restrict__ GP)
{
    const u16* A = (blockIdx.z >> 3) ? Bg : F;
    const int split = blockIdx.z & 7;
    __shared__ __align__(16) u16 As[128 * 64];
    __shared__ __align__(16) u16 Bs[128 * 64];
    const int tid  = threadIdx.x;
    const int wid  = tid >> 6;
    const int lane = tid & 63;
    const int wm = (wid >> 1) * 64;
    const int wn = (wid & 1) * 64;
    const size_t bm = (size_t)blockIdx.y * 128;
    const size_t bn = (size_t)blockIdx.x * 128;

    f32x4 acc[4][4];
#pragma unroll
    for (int i = 0; i < 4; ++i)
#pragma unroll
        for (int j = 0; j < 4; ++j)
            acc[i][j] = (f32x4){0.f, 0.f, 0.f, 0.f};

    const int lrow = lane >> 3;
    const int lcb  = ((lane & 7) << 4) ^ ((lrow & 7) << 4);
    const char* gR = (const char*)A + ((bm + wid * 32 + lrow) * (size_t)9216) * 2 + lcb;
    const char* gC = (const char*)A + ((bn + wid * 32 + lrow) * (size_t)9216) * 2 + lcb;
    char* lA = (char*)As + (size_t)(wid * 32) * 128;
    char* lB = (char*)Bs + (size_t)(wid * 32) * 128;
    const size_t rs8 = (size_t)9216 * 16;
    const int kbeg = split * 1152;

    for (int k0 = kbeg; k0 < kbeg + 1152; k0 += 64) {
        __syncthreads();
#pragma unroll
        for (int j = 0; j < 4; ++j) {
            GLOAD16(gR + j * rs8 + (size_t)k0 * 2, lA + j * 1024);
            GLOAD16(gC + j * rs8 + (size_t)k0 * 2, lB + j * 1024);
        }
        __syncthreads();
#pragma unroll
        for (int ks = 0; ks < 2; ++ks) {
            short8v a[4], b[4];
#pragma unroll
            for (int f = 0; f < 4; ++f) {
                int ma = wm + f * 16 + (lane & 15);
                int kba = (ks * 64 + ((lane >> 4) * 16)) ^ ((ma & 7) << 4);
                a[f] = *(const short8v*)((const char*)As + ma * 128 + kba);
                int nb = wn + f * 16 + (lane & 15);
                int kbb = (ks * 64 + ((lane >> 4) * 16)) ^ ((nb & 7) << 4);
                b[f] = *(const short8v*)((const char*)Bs + nb * 128 + kbb);
            }
#pragma unroll
            for (int fm = 0; fm < 4; ++fm)
#pragma unroll
                for (int fn = 0; fn < 4; ++fn)
                    acc[fm][fn] = __builtin_amdgcn_mfma_f32_16x16x32_bf16(
                        a[fm], b[fn], acc[fm][fn], 0, 0, 0);
        }
    }

    float* out = GP + (size_t)blockIdx.z * 1327104;
#pragma unroll
    for (int fm = 0; fm < 4; ++fm)
#pragma unroll
        for (int fn = 0; fn < 4; ++fn)
#pragma unroll
            for (int i = 0; i < 4; ++i) {
                int r = wm + fm * 16 + ((lane >> 4) * 4) + i;
                int c = wn + fn * 16 + (lane & 15);
                out[(bm + r) * 1152 + bn + c] = acc[fm][fn][i];
            }
}

// dot over summed split-K partials (8 fg + 8 bg, fixed order)
__global__ void dot_gram_stage1(const float* __restrict__ GP, double* __restrict__ partial)
{
    const size_t n = 1327104;
    size_t i = (size_t)blockIdx.x * 256 + threadIdx.x;
    size_t stride = (size_t)gridDim.x * 256;
    double s = 0.0;
    for (; i < n; i += stride) {
        float gf = 0.f, gb = 0.f;
#pragma unroll
        for (int j = 0; j < 8; ++j) gf += GP[(size_t)j * n + i];
#pragma unroll
        for (int j = 8; j < 16; ++j) gb += GP[(size_t)j * n + i];
        s += (double)gf * (double)gb;
    }
    for (int off = 32; off; off >>= 1) s += __shfl_down(s, off, 64);
    __shared__ double wsum[4];
    int lane = threadIdx.x & 63, wid = threadIdx.x >> 6;
    if (lane == 0) wsum[wid] = s;
    __syncthreads();
    if (threadIdx.x == 0) partial[blockIdx.x] = wsum[0] + wsum[1] + wsum[2] + wsum[3];
}

__global__ void sumsq_stage2(const double* __restrict__ partial, int nblocks, float* __restrict__ scale)
{
    double s = 0.0;
    for (int i = threadIdx.x; i < nblocks; i += 256) s += partial[i];
    for (int off = 32; off; off >>= 1) s += __shfl_down(s, off, 64);
    __shared__ double wsum[4];
    int lane = threadIdx.x & 63, wid = threadIdx.x >> 6;
    if (lane == 0) wsum[wid] = s;
    __syncthreads();
    if (threadIdx.x == 0) {
        double nrm = sqrt(wsum[0] + wsum[1] + wsum[2] + wsum[3]);
        if (nrm < 1e-12) nrm = 1e-12;
        *scale = (float)(10.0 / nrm);
    }
}

__global__ void inv_kernel(const float* __restrict__ rsP, float* __restrict__ inv)
{
    int i = blockIdx.x * 256 + threadIdx.x;
    if (i >= 9216) return;
    const float4* rp = (const float4*)(rsP + (size_t)i * 144);
    float s = 0.f;
#pragma unroll
    for (int j = 0; j < 36; ++j) {
        float4 v = rp[j];
        s += v.x + v.y + v.z + v.w;
    }
    inv[i] = 1.f / s;
}

// ---------------- fold + mask + upsample (planar fp32 out) ------------------
__global__ void fold_mask_up_kernel(const float* __restrict__ R2,
                                    const float* __restrict__ inv,
                                    const float* __restrict__ mask,
                                    float* __restrict__ up)
{
    int idx = blockIdx.x * 256 + threadIdx.x; // 128*96*96
    if (idx >= 128 * 96 * 96) return;
    int x = idx % 96;
    int y = (idx / 96) % 96;
    int c = idx / (96 * 96);
    float s = 0.f;
#pragma unroll
    for (int dy = 0; dy < 3; ++dy) {
        int yy = y + 1 - dy;
        if (yy < 0 || yy >= 96) continue;
#pragma unroll
        for (int dx = 0; dx < 3; ++dx) {
            int xx = x + 1 - dx;
            if (xx < 0 || xx >= 96) continue;
            int pp = yy * 96 + xx;
            s += R2[(size_t)(c * 9 + dy * 3 + dx) * 9216 + pp] * inv[pp];
        }
    }
    s *= mask[(size_t)(2 * y) * 192 + 2 * x];
    size_t base = (size_t)c * 192 * 192;
    up[base + (size_t)(2 * y) * 192 + 2 * x]         = s;
    up[base + (size_t)(2 * y) * 192 + 2 * x + 1]     = s;
    up[base + (size_t)(2 * y + 1) * 192 + 2 * x]     = s;
    up[base + (size_t)(2 * y + 1) * 192 + 2 * x + 1] = s;
}

// ---------------------------------------------------------------------------
extern "C" void kernel_launch(void* const* d_in, const int* in_sizes, int n_in,
                              void* d_out, int out_size, void* d_ws, size_t ws_size,
                              hipStream_t stream)
{
    const float* x    = (const float*)d_in[0];
    const float* mask = (const float*)d_in[1];
    const float* w[8];
    const float* b[8];
    for (int i = 0; i < 8; ++i) {
        w[i] = (const float*)d_in[2 + 2 * i];
        b[i] = (const float*)d_in[3 + 2 * i];
    }
    char* ws = (char*)d_ws;
    dim3 blk(256);

    // byte offsets (liveness-audited; peak 171.3 MB)
    const size_t U_H1CL = 0;            // cl bf16 768^2 x32  (37,748,736)
    const size_t U_H2   = 37748736;     // ( 9,437,184)
    const size_t U_H3   = 47185920;     // (18,874,368)
    const size_t U_H4   = 66060288;     // ( 9,437,184)
    const size_t U_H5   = 75497472;
    const size_t U_H6   = 84934656;     // ends 94,371,840
    const size_t U_X4   = 94371840;     // ( 4,718,592) conv1 only
    const size_t U_FGPT = 0;            // (21,233,664) [h1cl/h2 dead]
    const size_t U_BGPT = 21233664;
    const size_t U_BGPK = 42467328;
    const size_t U_FGPK = 63700992;     // ends 84,934,656
    const size_t F_GP   = 84934656;     // 16 x 5,308,416 = 84,934,656; ends 169,869,312 [h6/x4 dead]
    const size_t U_P    = 63700992;     // (56,623,104) ends 120,324,096 [fgpK, GP dead]
    const size_t F_R2   = 120324096;    // (42,467,328) ends 162,791,424 [GP dead]
    const size_t F_RSP  = 162791424;    // ( 5,308,416) ends 168,099,840 [GP dead]
    const size_t F_INV  = 168099840;    // (36,864) ends 168,136,704
    const size_t U_WP1  = 169869312;    // ( 8,192)
    const size_t U_WP2  = 169877504;    // (18,432)
    const size_t U_WP3  = 169895936;    // (36,864)
    const size_t U_WP4  = 169932800;    // (147,456)
    const size_t U_WP5  = 170080256;    // (294,912)
    const size_t U_WP6  = 170375168;
    const size_t U_WP7  = 170670080;
    const size_t U_WP8  = 170964992;    // ends 171,259,904
    const size_t D_RED  = 171259904;    // (4,096)
    const size_t F_SCALE= 171264000;    // (256) -> peak 171,264,256
    const size_t F_UP   = 0;            // (18,874,368) [fgpT dead]
    const size_t U_UPCL = 18874368;     // ( 9,437,184)
    const size_t U_H7   = 28311552;
    const size_t F_H8   = 37748736;     // (18,874,368) ends 56,623,104 [bgpT/bgpK dead]

    u16* h1cl   = (u16*)(ws + U_H1CL);
    u16* h2     = (u16*)(ws + U_H2);
    u16* h3     = (u16*)(ws + U_H3);
    u16* h4     = (u16*)(ws + U_H4);
    u16* h5     = (u16*)(ws + U_H5);
    u16* h6     = (u16*)(ws + U_H6);
    u16* x4     = (u16*)(ws + U_X4);
    u16* fgpT   = (u16*)(ws + U_FGPT);
    u16* bgpT   = (u16*)(ws + U_BGPT);
    u16* bgpK   = (u16*)(ws + U_BGPK);
    u16* fgpK   = (u16*)(ws + U_FGPK);
    float* GP   = (float*)(ws + F_GP);
    u16* P      = (u16*)(ws + U_P);
    float* R2   = (float*)(ws + F_R2);
    float* rsP  = (float*)(ws + F_RSP);
    float* inv  = (float*)(ws + F_INV);
    u16* wp1    = (u16*)(ws + U_WP1);
    u16* wp2    = (u16*)(ws + U_WP2);
    u16* wp3    = (u16*)(ws + U_WP3);
    u16* wp4    = (u16*)(ws + U_WP4);
    u16* wp5    = (u16*)(ws + U_WP5);
    u16* wp6    = (u16*)(ws + U_WP6);
    u16* wp7    = (u16*)(ws + U_WP7);
    u16* wp8    = (u16*)(ws + U_WP8);
    double* red = (double*)(ws + D_RED);
    float* scale= (float*)(ws + F_SCALE);
    float* upP  = (float*)(ws + F_UP);
    u16* upCL   = (u16*)(ws + U_UPCL);
    u16* h7     = (u16*)(ws + U_H7);
    float* h8   = (float*)(ws + F_H8);

    // ---- prepack ----
    pack_w1_kernel<<<dim3(16), blk, 0, stream>>>(w[0], wp1);
    pack_w_kernel<<<dim3(36),  blk, 0, stream>>>(w[1], wp2, 32, 32);
    pack_w_kernel<<<dim3(72),  blk, 0, stream>>>(w[2], wp3, 64, 32);
    pack_w_kernel<<<dim3(288), blk, 0, stream>>>(w[3], wp4, 128, 64);
    pack_w_kernel<<<dim3(576), blk, 0, stream>>>(w[4], wp5, 128, 128);
    pack_w_kernel<<<dim3(576), blk, 0, stream>>>(w[5], wp6, 128, 128);
    pack_w_kernel<<<dim3(576), blk, 0, stream>>>(w[6], wp7, 128, 128);
    pack_w_kernel<<<dim3(576), blk, 0, stream>>>(w[7], wp8, 128, 128);
    x4cl_kernel<<<dim3(2304), blk, 0, stream>>>(x, x4);

    // ---- conv front-end ----
    conv1_mfma_kernel<<<dim3(48, 96), blk, 0, stream>>>(x4, wp1, b[0], h1cl);
    mfma_conv_kernel<4, 1, 2, 2, 2, 32, 32, 1, 0><<<dim3(24, 48), blk, 0, stream>>>(
        h1cl, wp2, b[1], h2, 768, 768, 384, 384, 32);
    mfma_conv_kernel<4, 2, 2, 2, 1, 32, 32, 1, 0><<<dim3(24, 48), blk, 0, stream>>>(
        h2, wp3, b[2], h3, 384, 384, 384, 384, 64);
    mfma_conv_kernel<4, 2, 2, 2, 2, 64, 32, 1, 0><<<dim3(12, 24, 2), blk, 0, stream>>>(
        h3, wp4, b[3], h4, 384, 384, 192, 192, 128);
    mfma_conv_kernel<4, 2, 2, 2, 1, 128, 128, 1, 0><<<dim3(12, 24, 2), blk, 0, stream>>>(
        h4, wp5, b[4], h5, 192, 192, 192, 192, 128);
    mfma_conv_kernel<4, 2, 2, 2, 1, 128, 128, 0, 0><<<dim3(12, 24, 2), blk, 0, stream>>>(
        h5, wp6, b[5], h6, 192, 192, 192, 192, 128);

    // ---- patch matrices ----
    build_patches_T<<<dim3(41472), blk, 0, stream>>>(h6, mask, fgpT, bgpT);
    build_patches_K<<<dim3(41472), blk, 0, stream>>>(h6, mask, fgpK, bgpK);

    // ---- norm scale via Gram trick (16-way split, 1296 blocks) ----
    gram_kernel<<<dim3(9, 9, 16), blk, 0, stream>>>(fgpK, bgpK, GP);
    dot_gram_stage1<<<dim3(512), blk, 0, stream>>>(GP, red);
    sumsq_stage2<<<dim3(1), blk, 0, stream>>>(red, 512, scale);

    // ---- 3 q-stripes of 3072: S-exp -> P (fused row-partials), PV 64x128 ----
    for (int s = 0; s < 3; ++s) {
        size_t qs = (size_t)s * 3072;
        mfma_nt_sexp_kernel<<<dim3(24, 72), blk, 0, stream>>>(
            fgpT, bgpT + qs * 1152, 1152, 1152, 1152, P, 3072, scale, rsP, s * 48);
        if (s == 0)
            pv64_kernel<0><<<dim3(72, 18), blk, 0, stream>>>(
                bgpK + qs, P, 9216, 3072, 3072, R2, 9216);
        else
            pv64_kernel<1><<<dim3(72, 18), blk, 0, stream>>>(
                bgpK + qs, P, 9216, 3072, 3072, R2, 9216);
    }
    inv_kernel<<<dim3(36), blk, 0, stream>>>(rsP, inv);
    fold_mask_up_kernel<<<dim3(4608), blk, 0, stream>>>(R2, inv, mask, upP);

    // ---- back-end convs ----
    p2cl_kernel<<<dim3(1152), blk, 0, stream>>>(upP, upCL);
    mfma_conv_kernel<4, 2, 2, 2, 1, 128, 128, 1, 0><<<dim3(12, 24, 2), blk, 0, stream>>>(
        upCL, wp7, b[6], h7, 192, 192, 192, 192, 128);
    mfma_conv_kernel<4, 2, 2, 2, 1, 128, 128, 1, 1><<<dim3(12, 24, 2), blk, 0, stream>>>(
        h7, wp8, b[7], h8, 192, 192, 192, 192, 128);
    cl2p_kernel<<<dim3(1152), blk, 0, stream>>>(h8, (float*)d_out);
}